// Round 5
// baseline (487.314 us; speedup 1.0000x reference)
//
#include <hip/hip_runtime.h>
#include <cstdint>
#include <cmath>

#define Bn 4096
#define Dn 256
#define On 256

typedef __bf16 v8bf __attribute__((ext_vector_type(8)));
typedef float  v4f  __attribute__((ext_vector_type(4)));
typedef unsigned short us8 __attribute__((ext_vector_type(8)));

__device__ __forceinline__ unsigned short f2bf(float f) {
    // round-to-nearest-even fp32 -> bf16 (inputs are finite normals)
    unsigned int u = __builtin_bit_cast(unsigned int, f);
    unsigned int r = (u + 0x7fffu + ((u >> 16) & 1u)) >> 16;
    return (unsigned short)r;
}

__device__ __forceinline__ void gl_lds16(const void* g, void* l) {
    __builtin_amdgcn_global_load_lds(
        (const __attribute__((address_space(1))) void*)(uintptr_t)g,
        (__attribute__((address_space(3))) void*)(uintptr_t)l, 16, 0, 0);
}

// ---------------------------------------------------------------------------
// Kernel 1: FUSED prep. Blocks [0,2560): build A' = pre-swizzled MFMA
// A-operand layout of (triu(rots,1)+triu^T+diag(scales)) in bf16:
//   A'[o][s][k][lane][j] = A[o][i = s*16 + (lane&15)][kcol = k*32 + (lane>>4)*8 + j]
// (one 1KB block per (o, i-strip s, 32-wide kstep k); fuzzy_main loads a whole
// A-fragment as ONE coalesced global_load_dwordx4 — no LDS staging for A).
// One block per unordered 64x64 tile pair (10/o). Blocks [2560,2816): x->bf16.
// ---------------------------------------------------------------------------
__global__ __launch_bounds__(256) void prep(
    const float* __restrict__ scales, const float* __restrict__ rots,
    const float* __restrict__ x, unsigned short* __restrict__ Ap,
    unsigned short* __restrict__ xb) {
    const int bid = blockIdx.x;
    const int tid = threadIdx.x;

    if (bid >= 2560) {                   // ---- cvt_x part: 256 blocks ----
        const int cb = bid - 2560;
#pragma unroll
        for (int s = 0; s < 4; ++s) {
            const int i = cb * 4096 + s * 1024 + tid * 4;
            const float4 v = *(const float4*)(x + i);
            ushort4 u;
            u.x = f2bf(v.x); u.y = f2bf(v.y); u.z = f2bf(v.z); u.w = f2bf(v.w);
            *(ushort4*)(xb + i) = u;
        }
        return;
    }

    // ---- build_A' part: 2560 blocks, one per unordered 64x64 tile pair ----
    static const int TI[10] = {0, 0, 0, 0, 1, 1, 1, 2, 2, 3};
    static const int TJ[10] = {0, 1, 2, 3, 1, 2, 3, 2, 3, 3};
    const int o  = bid / 10;
    const int p  = bid - o * 10;
    const int ti = TI[p], tj = TJ[p];

    __shared__ float t[64][68];          // 68: keeps rows 16B-aligned, pads banks
    const float* src = rots + (size_t)o * Dn * Dn + (size_t)(ti * 64) * Dn + tj * 64;
#pragma unroll
    for (int s = 0; s < 4; ++s) {
        const int idx = s * 256 + tid;
        const int r = idx >> 4, c = (idx & 15) * 4;
        const float4 v = *(const float4*)(src + r * Dn + c);
        *(float4*)&t[r][c] = v;
    }
    __syncthreads();

    // phase U: output tile (ti,tj) -> A' blocks s=ti*4+sl, k=tj*2+kl
#pragma unroll
    for (int it = 0; it < 2; ++it) {
        const int slot = it * 256 + tid;
        const int bk = slot >> 6, L = slot & 63;
        const int quad = L >> 4, frow = L & 15;
        const int sl = bk >> 1, kl = bk & 1;
        const int r = sl * 16 + frow, c = kl * 32 + quad * 8;
        float v[8];
        if (ti == tj) {
#pragma unroll
            for (int q = 0; q < 8; ++q) {
                const int cc = c + q;
                v[q] = (r < cc) ? t[r][cc]
                     : ((r > cc) ? t[cc][r] : scales[o * Dn + ti * 64 + r]);
            }
        } else {
            const float4 a = *(const float4*)&t[r][c];
            const float4 b = *(const float4*)&t[r][c + 4];
            v[0] = a.x; v[1] = a.y; v[2] = a.z; v[3] = a.w;
            v[4] = b.x; v[5] = b.y; v[6] = b.z; v[7] = b.w;
        }
        us8 u;
#pragma unroll
        for (int q = 0; q < 8; ++q) u[q] = f2bf(v[q]);
        const size_t off = ((size_t)((o * 16 + ti * 4 + sl) * 8 + tj * 2 + kl)) * 512 + L * 8;
        *(us8*)(Ap + off) = u;           // 64 consecutive L -> 1KB coalesced
    }

    if (ti != tj) {                      // phase L: mirror tile (tj,ti), transposed
#pragma unroll
        for (int it = 0; it < 2; ++it) {
            const int slot = it * 256 + tid;
            const int bk = slot >> 6, L = slot & 63;
            const int quad = L >> 4, frow = L & 15;
            const int sl = bk >> 1, kl = bk & 1;
            const int r = sl * 16 + frow, c = kl * 32 + quad * 8;
            us8 u;
#pragma unroll
            for (int q = 0; q < 8; ++q) u[q] = f2bf(t[c + q][r]);
            const size_t off = ((size_t)((o * 16 + tj * 4 + sl) * 8 + ti * 2 + kl)) * 512 + L * 8;
            *(us8*)(Ap + off) = u;
        }
    }
}

// ---------------------------------------------------------------------------
// Kernel 2: fused GEMM + norm + bell, FOUR o's per block.
// Xs staged ONCE as 4 chunks [128 rows][64 k] (row stride 128 B — the layout
// empirically proven 0-conflict in rounds 1-2; round 4's 512 B stride caused
// 8.4e6 conflicts with identical slot algebra). Then 4 o-passes, each a
// barrier-free K-loop: 8 ksteps x {4 coalesced global A-frag loads (ping-pong
// prefetch), 8 ds_read_b128, 32 mfma_16x16x32_bf16}. Final store: float4 of
// 4 o-memberships per b row (no transpose kernel, low write amplification).
// Grid 2048; XCD-aware decode pins each o-group to one XCD (A' L2-resident).
// ---------------------------------------------------------------------------
__global__ __launch_bounds__(256, 2) void fuzzy_main(
    const unsigned short* __restrict__ Ap, const unsigned short* __restrict__ xb,
    const float* __restrict__ cent, const float* __restrict__ bvals,
    float* __restrict__ out) {
    __shared__ __align__(16) unsigned short Xs[4][128 * 64];  // 64 KB
    __shared__ float ssbufA[4][4][128];                        // [opass][wave][b] 8 KB
    __shared__ float centL[4][Dn];                             // 4 KB

    const int tid  = threadIdx.x;
    const int lane = tid & 63;
    const int wv   = tid >> 6;
    // XCD-aware decode: 2048 blocks = 8 XCD x 32 btile x 8 og-low
    const int Lb = blockIdx.x;
    const int og = (Lb & 7) * 8 + (Lb >> 8);       // o-group, 0..63 (4 o's each)
    const int b0 = ((Lb >> 3) & 31) * 128;

#pragma unroll
    for (int op = 0; op < 4; ++op)
        centL[op][tid] = cent[(og * 4 + op) * Dn + tid];

    const int frow = lane & 15, quad = lane >> 4, f3 = lane & 7;
    const int lr = lane >> 3, ls = lane & 7;
    const int ksw = (ls ^ lr) * 8;       // swizzled source k-offset within chunk

    // stage Xs once: per chunk c, 16 regions of 1KB (8 rows each), 4 per wave.
    // dest = chunk base + reg*1024B + lane*16B (wave-uniform + lane*16) ✓
#pragma unroll
    for (int c = 0; c < 4; ++c)
#pragma unroll
        for (int q = 0; q < 4; ++q) {
            const int row = (wv * 4 + q) * 8 + lr;
            gl_lds16(xb + (size_t)(b0 + row) * Dn + c * 64 + ksw,
                     &Xs[c][row * 64 + ls * 8]);
        }
    __syncthreads();   // the ONLY barrier before the final one

    for (int op = 0; op < 4; ++op) {
        const int o = og * 4 + op;
        const unsigned short* Aw = Ap + (size_t)(o * 16 + wv * 4) * 4096;
        // A-frag for (strip mi, kstep t): Aw + (mi*8 + t)*512 + lane*8 (1KB/frag)

        v4f acc[4][8];
#pragma unroll
        for (int mi = 0; mi < 4; ++mi)
#pragma unroll
            for (int ni = 0; ni < 8; ++ni)
                acc[mi][ni] = v4f{0.f, 0.f, 0.f, 0.f};

        v8bf af[2][4];
#pragma unroll
        for (int mi = 0; mi < 4; ++mi)
            af[0][mi] = *(const v8bf*)(Aw + (size_t)mi * 8 * 512 + lane * 8);

#pragma unroll
        for (int t = 0; t < 8; ++t) {
            const int cur = t & 1, nxt = cur ^ 1;
            if (t < 7) {
#pragma unroll
                for (int mi = 0; mi < 4; ++mi)
                    af[nxt][mi] = *(const v8bf*)(Aw + (size_t)(mi * 8 + t + 1) * 512 + lane * 8);
            }
            v8bf xf[8];
            const int sl = ((t & 1) * 4 + quad) ^ f3;   // proven 0-conflict class
#pragma unroll
            for (int ni = 0; ni < 8; ++ni)
                xf[ni] = *(const v8bf*)&Xs[t >> 1][(ni * 16 + frow) * 64 + sl * 8];
#pragma unroll
            for (int mi = 0; mi < 4; ++mi)
#pragma unroll
                for (int ni = 0; ni < 8; ++ni)
                    acc[mi][ni] = __builtin_amdgcn_mfma_f32_16x16x32_bf16(
                        af[cur][mi], xf[ni], acc[mi][ni], 0, 0, 0);
        }

        // epilogue: y = acc + centroid; partial sum_i y^2 for this wave's 64 i
        float cv[4][4];
#pragma unroll
        for (int mi = 0; mi < 4; ++mi)
#pragma unroll
            for (int rg = 0; rg < 4; ++rg)
                cv[mi][rg] = centL[op][wv * 64 + mi * 16 + quad * 4 + rg];
#pragma unroll
        for (int ni = 0; ni < 8; ++ni) {
            float v = 0.f;
#pragma unroll
            for (int mi = 0; mi < 4; ++mi)
#pragma unroll
                for (int rg = 0; rg < 4; ++rg) {
                    const float y = acc[mi][ni][rg] + cv[mi][rg];
                    v += y * y;
                }
            v += __shfl_xor(v, 16);
            v += __shfl_xor(v, 32);
            if (lane < 16) ssbufA[op][wv][ni * 16 + lane] = v;
        }
    }
    __syncthreads();
    if (tid < 128) {
        float4 r;
        float* rp = &r.x;
#pragma unroll
        for (int op = 0; op < 4; ++op) {
            const float ssq = ssbufA[op][0][tid] + ssbufA[op][1][tid] +
                              ssbufA[op][2][tid] + ssbufA[op][3][tid];
            rp[op] = 1.0f / (1.0f + powf(ssq, bvals[og * 4 + op]));
        }
        *(float4*)(out + (size_t)(b0 + tid) * On + og * 4) = r;
    }
}

// ---------------------------------------------------------------------------
// Fallback (only if d_ws is too small): exact fp32, slow but correct.
// ---------------------------------------------------------------------------
__global__ void fallback_kernel(const float* __restrict__ x, const float* __restrict__ scales,
                                const float* __restrict__ rots, const float* __restrict__ cent,
                                const float* __restrict__ bvals, float* __restrict__ out) {
    const int b = blockIdx.x * blockDim.x + threadIdx.x;
    const int o = blockIdx.y;
    if (b >= Bn) return;
    const float* R  = rots + (size_t)o * Dn * Dn;
    const float* xv = x + (size_t)b * Dn;
    float ss = 0.f;
    for (int i = 0; i < Dn; ++i) {
        float a = cent[o * Dn + i];
        for (int j = 0; j < Dn; ++j) {
            const float w = (j > i) ? R[i * Dn + j]
                          : ((j < i) ? R[j * Dn + i] : scales[o * Dn + i]);
            a += w * xv[j];
        }
        ss += a * a;
    }
    out[(size_t)b * On + o] = 1.f / (1.f + powf(ss, bvals[o]));
}

extern "C" void kernel_launch(void* const* d_in, const int* in_sizes, int n_in,
                              void* d_out, int out_size, void* d_ws, size_t ws_size,
                              hipStream_t stream) {
    const float* x         = (const float*)d_in[0];
    const float* scales    = (const float*)d_in[1];
    const float* rots      = (const float*)d_in[2];
    const float* centroids = (const float*)d_in[3];
    const float* bvals     = (const float*)d_in[4];
    float* out = (float*)d_out;

    const size_t needA = (size_t)On * Dn * Dn * sizeof(unsigned short); // 33.5 MB
    const size_t needX = (size_t)Bn * Dn * sizeof(unsigned short);      //  2.1 MB

    if (ws_size >= needA + needX) {
        unsigned short* Ap = (unsigned short*)d_ws;
        unsigned short* xb = (unsigned short*)((char*)d_ws + needA);
        prep<<<dim3(2816), 256, 0, stream>>>(scales, rots, x, Ap, xb);
        fuzzy_main<<<dim3(2048), 256, 0, stream>>>(Ap, xb, centroids, bvals, out);
    } else {
        fallback_kernel<<<dim3(Bn / 256, On), 256, 0, stream>>>(x, scales, rots, centroids,
                                                                bvals, out);
    }
}

// Round 6
// 245.679 us; speedup vs baseline: 1.9835x; 1.9835x over previous
//
#include <hip/hip_runtime.h>
#include <cstdint>
#include <cmath>

#define Bn 4096
#define Dn 256
#define On 256

typedef __bf16 v8bf __attribute__((ext_vector_type(8)));
typedef float  v4f  __attribute__((ext_vector_type(4)));
typedef unsigned short us8 __attribute__((ext_vector_type(8)));

__device__ __forceinline__ unsigned short f2bf(float f) {
    // round-to-nearest-even fp32 -> bf16 (inputs are finite normals)
    unsigned int u = __builtin_bit_cast(unsigned int, f);
    unsigned int r = (u + 0x7fffu + ((u >> 16) & 1u)) >> 16;
    return (unsigned short)r;
}

__device__ __forceinline__ void gl_lds16(const void* g, void* l) {
    __builtin_amdgcn_global_load_lds(
        (const __attribute__((address_space(1))) void*)(uintptr_t)g,
        (__attribute__((address_space(3))) void*)(uintptr_t)l, 16, 0, 0);
}

// ---------------------------------------------------------------------------
// Kernel 1: FUSED prep. Blocks [0,2560): build A' = pre-swizzled MFMA
// A-operand layout of (triu(rots,1)+triu^T+diag(scales)) in bf16:
//   A'[o][s][k][lane][j] = A[o][i = s*16 + (lane&15)][kcol = k*32 + (lane>>4)*8 + j]
// (one 1KB block per (o, i-strip s, 32-wide kstep k); fuzzy_main loads a whole
// A-fragment as ONE coalesced global_load_dwordx4 — no LDS staging for A).
// One block per unordered 64x64 tile pair (10/o). Blocks [2560,2816): x->bf16.
// ---------------------------------------------------------------------------
__global__ __launch_bounds__(256) void prep(
    const float* __restrict__ scales, const float* __restrict__ rots,
    const float* __restrict__ x, unsigned short* __restrict__ Ap,
    unsigned short* __restrict__ xb) {
    const int bid = blockIdx.x;
    const int tid = threadIdx.x;

    if (bid >= 2560) {                   // ---- cvt_x part: 256 blocks ----
        const int cb = bid - 2560;
#pragma unroll
        for (int s = 0; s < 4; ++s) {
            const int i = cb * 4096 + s * 1024 + tid * 4;
            const float4 v = *(const float4*)(x + i);
            ushort4 u;
            u.x = f2bf(v.x); u.y = f2bf(v.y); u.z = f2bf(v.z); u.w = f2bf(v.w);
            *(ushort4*)(xb + i) = u;
        }
        return;
    }

    // ---- build_A' part: 2560 blocks, one per unordered 64x64 tile pair ----
    static const int TI[10] = {0, 0, 0, 0, 1, 1, 1, 2, 2, 3};
    static const int TJ[10] = {0, 1, 2, 3, 1, 2, 3, 2, 3, 3};
    const int o  = bid / 10;
    const int p  = bid - o * 10;
    const int ti = TI[p], tj = TJ[p];

    __shared__ float t[64][68];          // 68: keeps rows 16B-aligned, pads banks
    const float* src = rots + (size_t)o * Dn * Dn + (size_t)(ti * 64) * Dn + tj * 64;
#pragma unroll
    for (int s = 0; s < 4; ++s) {
        const int idx = s * 256 + tid;
        const int r = idx >> 4, c = (idx & 15) * 4;
        const float4 v = *(const float4*)(src + r * Dn + c);
        *(float4*)&t[r][c] = v;
    }
    __syncthreads();

    // phase U: output tile (ti,tj) -> A' blocks s=ti*4+sl, k=tj*2+kl
#pragma unroll
    for (int it = 0; it < 2; ++it) {
        const int slot = it * 256 + tid;
        const int bk = slot >> 6, L = slot & 63;
        const int quad = L >> 4, frow = L & 15;
        const int sl = bk >> 1, kl = bk & 1;
        const int r = sl * 16 + frow, c = kl * 32 + quad * 8;
        float v[8];
        if (ti == tj) {
#pragma unroll
            for (int q = 0; q < 8; ++q) {
                const int cc = c + q;
                v[q] = (r < cc) ? t[r][cc]
                     : ((r > cc) ? t[cc][r] : scales[o * Dn + ti * 64 + r]);
            }
        } else {
            const float4 a = *(const float4*)&t[r][c];
            const float4 b = *(const float4*)&t[r][c + 4];
            v[0] = a.x; v[1] = a.y; v[2] = a.z; v[3] = a.w;
            v[4] = b.x; v[5] = b.y; v[6] = b.z; v[7] = b.w;
        }
        us8 u;
#pragma unroll
        for (int q = 0; q < 8; ++q) u[q] = f2bf(v[q]);
        const size_t off = ((size_t)((o * 16 + ti * 4 + sl) * 8 + tj * 2 + kl)) * 512 + L * 8;
        *(us8*)(Ap + off) = u;           // 64 consecutive L -> 1KB coalesced
    }

    if (ti != tj) {                      // phase L: mirror tile (tj,ti), transposed
#pragma unroll
        for (int it = 0; it < 2; ++it) {
            const int slot = it * 256 + tid;
            const int bk = slot >> 6, L = slot & 63;
            const int quad = L >> 4, frow = L & 15;
            const int sl = bk >> 1, kl = bk & 1;
            const int r = sl * 16 + frow, c = kl * 32 + quad * 8;
            us8 u;
#pragma unroll
            for (int q = 0; q < 8; ++q) u[q] = f2bf(t[c + q][r]);
            const size_t off = ((size_t)((o * 16 + tj * 4 + sl) * 8 + ti * 2 + kl)) * 512 + L * 8;
            *(us8*)(Ap + off) = u;
        }
    }
}

// ---------------------------------------------------------------------------
// Kernel 2: fused GEMM (y = A[o] x + c) + squared-norm + bell membership.
// ROUND-4 STRUCTURE (grid 8192, 1 o/block, 2 live o's per XCD L2 -> 24.8 MB
// FETCH proven) with ROUND-5's Xs layout (4 chunks [128 rows][64 k], 128 B row
// stride -> 0 bank conflicts proven; round 4's 512 B stride cost 8.4e6).
// Barrier-free K-loop: Xs staged once, one __syncthreads, then 8 unrolled
// ksteps x {4 coalesced global A-frag loads (ping-pong prefetch from L2),
// 8 ds_read_b128, 32 mfma_16x16x32_bf16}. acc[4][8] = 128 AGPR; total regs
// pinned at the 256 boundary (2 waves/SIMD) — deliberately no xf register
// double-buffer, which would tip past 256 and halve occupancy.
// ---------------------------------------------------------------------------
__global__ __launch_bounds__(256, 2) void fuzzy_main(
    const unsigned short* __restrict__ Ap, const unsigned short* __restrict__ xb,
    const float* __restrict__ cent, const float* __restrict__ bvals,
    float* __restrict__ obase, int sb, int so) {
    __shared__ __align__(16) unsigned short Xs[4][128 * 64];  // 64 KB
    __shared__ float ssbuf[4][128];
    __shared__ float centL[Dn];

    const int tid  = threadIdx.x;
    const int lane = tid & 63;
    const int wv   = tid >> 6;
    // XCD-aware decode (round-4 proven): ~2 live o's per XCD -> A' L2-resident
    const int Lb = blockIdx.x;
    const int o  = (Lb & 7) * 32 + (Lb >> 8);
    const int b0 = ((Lb >> 3) & 31) * 128;

    centL[tid] = cent[o * Dn + tid];

    const int frow = lane & 15, quad = lane >> 4, f3 = lane & 7;
    const int lr = lane >> 3, ls = lane & 7;
    const int ksw = (ls ^ lr) * 8;       // swizzled source k-offset within chunk

    // stage Xs once: per chunk c, 16 regions of 1KB (8 rows each), 4 per wave.
    // dest = chunk base + reg*1024B + lane*16B (wave-uniform + lane*16) ✓
#pragma unroll
    for (int c = 0; c < 4; ++c)
#pragma unroll
        for (int q = 0; q < 4; ++q) {
            const int row = (wv * 4 + q) * 8 + lr;
            gl_lds16(xb + (size_t)(b0 + row) * Dn + c * 64 + ksw,
                     &Xs[c][row * 64 + ls * 8]);
        }

    const unsigned short* Aw = Ap + (size_t)(o * 16 + wv * 4) * 4096;
    // A-frag for (strip mi, kstep t): Aw + (mi*8 + t)*512 + lane*8 (1KB/frag)

    v4f acc[4][8];
#pragma unroll
    for (int mi = 0; mi < 4; ++mi)
#pragma unroll
        for (int ni = 0; ni < 8; ++ni)
            acc[mi][ni] = v4f{0.f, 0.f, 0.f, 0.f};

    v8bf af[2][4];
#pragma unroll
    for (int mi = 0; mi < 4; ++mi)       // t=0 A-frags: no barrier dependency
        af[0][mi] = *(const v8bf*)(Aw + (size_t)mi * 8 * 512 + lane * 8);

    __syncthreads();   // the ONLY barrier before the epilogue

#pragma unroll
    for (int t = 0; t < 8; ++t) {
        const int cur = t & 1, nxt = cur ^ 1;
        if (t < 7) {
#pragma unroll
            for (int mi = 0; mi < 4; ++mi)
                af[nxt][mi] = *(const v8bf*)(Aw + (size_t)(mi * 8 + t + 1) * 512 + lane * 8);
        }
        v8bf xf[8];
        const int sl = ((t & 1) * 4 + quad) ^ f3;   // proven 0-conflict class
#pragma unroll
        for (int ni = 0; ni < 8; ++ni)
            xf[ni] = *(const v8bf*)&Xs[t >> 1][(ni * 16 + frow) * 64 + sl * 8];
#pragma unroll
        for (int mi = 0; mi < 4; ++mi)
#pragma unroll
            for (int ni = 0; ni < 8; ++ni)
                acc[mi][ni] = __builtin_amdgcn_mfma_f32_16x16x32_bf16(
                    af[cur][mi], xf[ni], acc[mi][ni], 0, 0, 0);
    }

    // epilogue: y = acc + centroid; reduce sum_i y^2 (C/D: col=lane&15=b,
    // row=quad*4+rg=i) — verified in rounds 1-5.
    float cv[4][4];
#pragma unroll
    for (int mi = 0; mi < 4; ++mi)
#pragma unroll
        for (int rg = 0; rg < 4; ++rg)
            cv[mi][rg] = centL[wv * 64 + mi * 16 + quad * 4 + rg];
#pragma unroll
    for (int ni = 0; ni < 8; ++ni) {
        float v = 0.f;
#pragma unroll
        for (int mi = 0; mi < 4; ++mi)
#pragma unroll
            for (int rg = 0; rg < 4; ++rg) {
                const float y = acc[mi][ni][rg] + cv[mi][rg];
                v += y * y;
            }
        v += __shfl_xor(v, 16);
        v += __shfl_xor(v, 32);
        if (lane < 16) ssbuf[wv][ni * 16 + lane] = v;
    }
    __syncthreads();
    if (tid < 128) {
        const float ssq = ssbuf[0][tid] + ssbuf[1][tid] + ssbuf[2][tid] + ssbuf[3][tid];
        obase[(size_t)(b0 + tid) * sb + (size_t)o * so] =
            1.0f / (1.0f + powf(ssq, bvals[o]));
    }
}

// ---------------------------------------------------------------------------
// Kernel 3: transpose outT [O][B] -> out [B][O] (both coalesced, 64x64 tiles)
// ---------------------------------------------------------------------------
__global__ __launch_bounds__(256) void transp(const float* __restrict__ outT,
                                              float* __restrict__ out) {
    __shared__ float t[64][65];
    const int bb = blockIdx.x * 64;
    const int ob = blockIdx.y * 64;
    const int tid = threadIdx.x;
    const int r = tid >> 4;
    const int c = (tid & 15) * 4;
#pragma unroll
    for (int s = 0; s < 4; ++s) {
        const int rr = s * 16 + r;
        const float4 v = *(const float4*)(outT + (size_t)(ob + rr) * Bn + bb + c);
        t[rr][c] = v.x; t[rr][c + 1] = v.y; t[rr][c + 2] = v.z; t[rr][c + 3] = v.w;
    }
    __syncthreads();
#pragma unroll
    for (int s = 0; s < 4; ++s) {
        const int rr = s * 16 + r;
        float4 w;
        w.x = t[c][rr]; w.y = t[c + 1][rr]; w.z = t[c + 2][rr]; w.w = t[c + 3][rr];
        *(float4*)(out + (size_t)(bb + rr) * On + ob + c) = w;
    }
}

// ---------------------------------------------------------------------------
// Fallback (only if d_ws is too small): exact fp32, slow but correct.
// ---------------------------------------------------------------------------
__global__ void fallback_kernel(const float* __restrict__ x, const float* __restrict__ scales,
                                const float* __restrict__ rots, const float* __restrict__ cent,
                                const float* __restrict__ bvals, float* __restrict__ out) {
    const int b = blockIdx.x * blockDim.x + threadIdx.x;
    const int o = blockIdx.y;
    if (b >= Bn) return;
    const float* R  = rots + (size_t)o * Dn * Dn;
    const float* xv = x + (size_t)b * Dn;
    float ss = 0.f;
    for (int i = 0; i < Dn; ++i) {
        float a = cent[o * Dn + i];
        for (int j = 0; j < Dn; ++j) {
            const float w = (j > i) ? R[i * Dn + j]
                          : ((j < i) ? R[j * Dn + i] : scales[o * Dn + i]);
            a += w * xv[j];
        }
        ss += a * a;
    }
    out[(size_t)b * On + o] = 1.f / (1.f + powf(ss, bvals[o]));
}

extern "C" void kernel_launch(void* const* d_in, const int* in_sizes, int n_in,
                              void* d_out, int out_size, void* d_ws, size_t ws_size,
                              hipStream_t stream) {
    const float* x         = (const float*)d_in[0];
    const float* scales    = (const float*)d_in[1];
    const float* rots      = (const float*)d_in[2];
    const float* centroids = (const float*)d_in[3];
    const float* bvals     = (const float*)d_in[4];
    float* out = (float*)d_out;

    const size_t needA = (size_t)On * Dn * Dn * sizeof(unsigned short); // 33.5 MB
    const size_t needX = (size_t)Bn * Dn * sizeof(unsigned short);      //  2.1 MB
    const size_t needT = (size_t)On * Bn * sizeof(float);               //  4.2 MB

    if (ws_size >= needA + needX) {
        unsigned short* Ap = (unsigned short*)d_ws;
        unsigned short* xb = (unsigned short*)((char*)d_ws + needA);
        prep<<<dim3(2816), 256, 0, stream>>>(scales, rots, x, Ap, xb);
        if (ws_size >= needA + needX + needT) {
            float* outT = (float*)((char*)d_ws + needA + needX);
            fuzzy_main<<<dim3(8192), 256, 0, stream>>>(Ap, xb, centroids, bvals,
                                                       outT, 1, Bn);
            transp<<<dim3(Bn / 64, On / 64), 256, 0, stream>>>(outT, out);
        } else {
            fuzzy_main<<<dim3(8192), 256, 0, stream>>>(Ap, xb, centroids, bvals,
                                                       out, On, 1);
        }
    } else {
        fallback_kernel<<<dim3(Bn / 256, On), 256, 0, stream>>>(x, scales, rots, centroids,
                                                                bvals, out);
    }
}